// Round 6
// baseline (277.434 us; speedup 1.0000x reference)
//
#include <hip/hip_runtime.h>
#include <hip/hip_bf16.h>

// Problem: B=4, S=2048, D=1024, H=16, DH=64. M = B*S = 8192.
// Pipeline: prep(LN + weight cast) -> fused QKV proj (bf16 mfma, N=3072, BK=64)
//           -> flash attn (bf16 MFMA, paired q-tiles, batch-interleaved grid)
//           -> out proj (BK=64) + bias + skip (fp32 out)

#define Bn 4
#define Sn 2048
#define Dn 1024
#define Hn 16
#define DHn 64
#define Mn (Bn*Sn)

typedef short short8 __attribute__((ext_vector_type(8)));
typedef short short4v __attribute__((ext_vector_type(4)));
typedef unsigned short ushort8 __attribute__((ext_vector_type(8)));
typedef unsigned short ushort4v __attribute__((ext_vector_type(4)));
typedef float f32x4 __attribute__((ext_vector_type(4)));

__device__ inline float bf2f(unsigned short u) {
    union { unsigned int i; float f; } c;
    c.i = ((unsigned int)u) << 16;
    return c.f;
}

__device__ inline unsigned short f2bf(float f) {
    union { float f; unsigned int i; } c;
    c.f = f;
    unsigned int i = c.i;
    unsigned int lsb = (i >> 16) & 1;
    i += 0x7fffu + lsb;   // round-to-nearest-even
    return (unsigned short)(i >> 16);
}

// truncating fp32->bf16 (fine for p in [0,1])
__device__ inline unsigned short f2bf_t(float f) {
    union { float f; unsigned int i; } c;
    c.f = f;
    return (unsigned short)(c.i >> 16);
}

__device__ __forceinline__ float fast_exp2(float x) {
#if __has_builtin(__builtin_amdgcn_exp2f)
    return __builtin_amdgcn_exp2f(x);
#else
    return exp2f(x);
#endif
}

#if __has_builtin(__builtin_amdgcn_global_load_lds)
#define HAVE_GLDS 1
__device__ __forceinline__ void glds16(const void* g, void* l) {
    __builtin_amdgcn_global_load_lds(
        (const __attribute__((address_space(1))) unsigned int*)g,
        (__attribute__((address_space(3))) unsigned int*)l, 16, 0, 0);
}
#else
#define HAVE_GLDS 0
#endif

// ---------------- prep: LN (blocks 0..8191) + weight casts (blocks 8192..12287) ----------------
__global__ __launch_bounds__(256) void prep_kernel(const float* __restrict__ x,
                                                   const float* __restrict__ g,
                                                   const float* __restrict__ bta,
                                                   unsigned short* __restrict__ xn,
                                                   const float* __restrict__ Wq,
                                                   const float* __restrict__ Wkv,
                                                   const float* __restrict__ Wo,
                                                   unsigned short* __restrict__ oq,
                                                   unsigned short* __restrict__ okv,
                                                   unsigned short* __restrict__ oo) {
    const int t = threadIdx.x;
    if (blockIdx.x >= Mn) {
        int i = (blockIdx.x - Mn) * 256 + t;
        const float* src;
        unsigned short* dst;
        int off;
        if (i < 262144) { src = Wq; dst = oq; off = i; }
        else if (i < 786432) { src = Wkv; dst = okv; off = i - 262144; }
        else { src = Wo; dst = oo; off = i - 786432; }
        float4 v = *(const float4*)(src + (size_t)off * 4);
        ushort4v r;
        r.x = f2bf(v.x); r.y = f2bf(v.y); r.z = f2bf(v.z); r.w = f2bf(v.w);
        *(ushort4v*)(dst + (size_t)off * 4) = r;
        return;
    }
    const int row = blockIdx.x;
    const float* xr = x + (size_t)row * Dn;
    float4 v = *(const float4*)(xr + t * 4);
    float s = v.x + v.y + v.z + v.w;
    float sq = v.x * v.x + v.y * v.y + v.z * v.z + v.w * v.w;
    for (int off = 32; off; off >>= 1) {
        s += __shfl_down(s, off);
        sq += __shfl_down(sq, off);
    }
    __shared__ float ss[4], ssq[4];
    int wave = t >> 6, lane = t & 63;
    if (lane == 0) { ss[wave] = s; ssq[wave] = sq; }
    __syncthreads();
    float tot = ss[0] + ss[1] + ss[2] + ss[3];
    float totq = ssq[0] + ssq[1] + ssq[2] + ssq[3];
    float mean = tot * (1.0f / Dn);
    float var = totq * (1.0f / Dn) - mean * mean;
    float rstd = rsqrtf(var + 1e-5f);
    float4 gv = *(const float4*)(g + t * 4);
    float4 bv = *(const float4*)(bta + t * 4);
    ushort4v r;
    r.x = f2bf((v.x - mean) * rstd * gv.x + bv.x);
    r.y = f2bf((v.y - mean) * rstd * gv.y + bv.y);
    r.z = f2bf((v.z - mean) * rstd * gv.z + bv.z);
    r.w = f2bf((v.w - mean) * rstd * gv.w + bv.w);
    *(ushort4v*)(xn + (size_t)row * Dn + t * 4) = r;
}

// ---------------- bf16 BT-GEMM: C = A(MxK) * Bw(NxK)^T + bias ----------------
// 128x128 tile, 4 waves (2x2), 16x16x32 MFMA. BK=64 staged as TWO 32-col
// panels (each panel = the proven BK=32 layout, glds16-compatible) -> half the
// barrier count of BK=32 at the same staging rate. LDS 32 KB -> 5 blocks/CU.
template <bool ADD_SKIP, bool OUT_BF16>
__global__ __launch_bounds__(256, 2) void gemm_bt(const unsigned short* __restrict__ A,
                                                  const unsigned short* __restrict__ Bw,
                                                  const float* __restrict__ bias,
                                                  const float* __restrict__ bias2,
                                                  int bsplit,
                                                  const float* __restrict__ skip,
                                                  void* __restrict__ Cout,
                                                  int M, int N, int K) {
    __shared__ unsigned short As[2 * 128 * 32];   // [panel][row][32]
    __shared__ unsigned short Bs[2 * 128 * 32];
    const int tid = threadIdx.x;
    const int wave = tid >> 6, lane = tid & 63;
    const int warp_m = wave & 1, warp_n = wave >> 1;
    const int bm = blockIdx.x, bn = blockIdx.y;
    const int l4 = lane & 3, lr = lane >> 2;
    const int quad = lane >> 4, r16 = lane & 15;

    f32x4 acc[4][4];
#pragma unroll
    for (int i = 0; i < 4; i++)
#pragma unroll
        for (int j = 0; j < 4; j++) acc[i][j] = (f32x4){0.f, 0.f, 0.f, 0.f};

    for (int k0 = 0; k0 < K; k0 += 64) {
        __syncthreads();   // prev iteration's fragment readers done
#if HAVE_GLDS
#pragma unroll
        for (int ks = 0; ks < 2; ++ks) {
#pragma unroll
            for (int i = 0; i < 2; ++i) {
                int inst = wave + 4 * i;
                glds16(A + (size_t)(bm * 128 + inst * 16 + lr) * K + k0 + ks * 32 + l4 * 8,
                       &As[ks * 4096 + inst * 512]);
                glds16(Bw + (size_t)(bn * 128 + inst * 16 + lr) * K + k0 + ks * 32 + l4 * 8,
                       &Bs[ks * 4096 + inst * 512]);
            }
        }
#else
#pragma unroll
        for (int ks = 0; ks < 2; ++ks) {
#pragma unroll
            for (int i = 0; i < 2; ++i) {
                int inst = wave + 4 * i;
                int row = inst * 16 + lr;
                ushort8 a = *(const ushort8*)(A + (size_t)(bm * 128 + row) * K + k0 + ks * 32 + l4 * 8);
                ushort8 b2 = *(const ushort8*)(Bw + (size_t)(bn * 128 + row) * K + k0 + ks * 32 + l4 * 8);
                *(ushort8*)(As + ks * 4096 + inst * 512 + lane * 8) = a;
                *(ushort8*)(Bs + ks * 4096 + inst * 512 + lane * 8) = b2;
            }
        }
#endif
        __syncthreads();   // vmcnt drain: LDS populated

#pragma unroll
        for (int ks = 0; ks < 2; ++ks) {
            short8 afr[4], bfr[4];
#pragma unroll
            for (int i = 0; i < 4; ++i) {
                int row = warp_m * 64 + i * 16 + r16;
                afr[i] = *(const short8*)(As + ks * 4096 + row * 32 + quad * 8);
            }
#pragma unroll
            for (int j = 0; j < 4; ++j) {
                int row = warp_n * 64 + j * 16 + r16;
                bfr[j] = *(const short8*)(Bs + ks * 4096 + row * 32 + quad * 8);
            }
#pragma unroll
            for (int i = 0; i < 4; ++i)
#pragma unroll
                for (int j = 0; j < 4; ++j)
                    acc[i][j] = __builtin_amdgcn_mfma_f32_16x16x32_bf16(afr[i], bfr[j], acc[i][j], 0, 0, 0);
        }
    }

    const float* bp = (bn * 128 >= bsplit) ? (bias2 - bsplit) : bias;
#pragma unroll
    for (int j = 0; j < 4; ++j) {
        int gcol = bn * 128 + warp_n * 64 + j * 16 + r16;
        float bv = bp[gcol];
#pragma unroll
        for (int i = 0; i < 4; ++i) {
#pragma unroll
            for (int r = 0; r < 4; ++r) {
                int grow = bm * 128 + warp_m * 64 + i * 16 + quad * 4 + r;
                float v = acc[i][j][r] + bv;
                size_t idx = (size_t)grow * N + gcol;
                if (ADD_SKIP) v += skip[idx];
                if (OUT_BF16)
                    ((unsigned short*)Cout)[idx] = f2bf(v);
                else
                    ((float*)Cout)[idx] = v;
            }
        }
    }
}

// ---------------- MFMA flash attention, paired q-tiles ----------------
// 1D grid, batch/head fastest-varying so the longest batch's blocks spread
// across all CUs (kills the small-len-batch tail). Block handles q-tiles
// qtA and 31-qtA sharing K/V staging.
#define STK 72
#define STV 68
#define STP 72
#define QKVS (3 * Dn)   // fused QKV row stride

__global__ __launch_bounds__(256, 4) void attn_kernel(const unsigned short* __restrict__ QKV,
                                                      const int* __restrict__ lens,
                                                      unsigned short* __restrict__ Ctx) {
    const int b = blockIdx.x & 3;
    const int h = (blockIdx.x >> 2) & 15;
    const int qtA = blockIdx.x >> 6;            // 0..15
    const int qtB = (Sn / 64 - 1) - qtA;        // 31..16
    const int tid = threadIdx.x;
    const int wave = tid >> 6, lane = tid & 63;
    const int quad = lane >> 4, c = lane & 15;
    const int len = lens[b];
    const int lt = (len - 1) >> 6;
    const int ktendA = min(qtA, lt);
    const int ktendB = min(qtB, lt);            // >= ktendA always
    const int qwA = qtA * 64 + wave * 16;
    const int qwB = qtB * 64 + wave * 16;
    const int myqA = qwA + c, myqB = qwB + c;

    __shared__ unsigned short Ks[64 * STK];
    __shared__ unsigned short Vt[64 * STV];
    __shared__ unsigned short Ps[4][16 * STP];

    // Q fragments for both chunks (B-operand layout)
    short8 qfA[2], qfB[2];
    {
        const unsigned short* qa = QKV + (size_t)(b * Sn + qwA + c) * QKVS + h * 64 + quad * 8;
        qfA[0] = *(const short8*)(qa);
        qfA[1] = *(const short8*)(qa + 32);
        const unsigned short* qb = QKV + (size_t)(b * Sn + qwB + c) * QKVS + h * 64 + quad * 8;
        qfB[0] = *(const short8*)(qb);
        qfB[1] = *(const short8*)(qb + 32);
    }

    f32x4 accA[4], accB[4];
#pragma unroll
    for (int j = 0; j < 4; j++) {
        accA[j] = (f32x4){0.f, 0.f, 0.f, 0.f};
        accB[j] = (f32x4){0.f, 0.f, 0.f, 0.f};
    }
    float mA = -1e30f, lA = 0.f, mB = -1e30f, lB = 0.f;

    // staging thread mappings
    const int krow = tid >> 2, dp = tid & 3;   // K: row krow, 16-col chunk dp
    const int kg = tid >> 4, dg = tid & 15;    // V: k rows kg*4..+3, dh cols dg*4..+3
    const unsigned short* kbase = QKV + (size_t)(b * Sn) * QKVS + Dn + h * 64;        // K cols
    const unsigned short* vbase = QKV + (size_t)(b * Sn) * QKVS + 2 * Dn + h * 64;    // V cols

    // prologue: prefetch tile 0
    ushort8 kr0, kr1;
    ushort4v vr0, vr1, vr2, vr3;
    {
        const unsigned short* kp2 = kbase + (size_t)krow * QKVS + dp * 16;
        kr0 = *(const ushort8*)(kp2);
        kr1 = *(const ushort8*)(kp2 + 8);
        const unsigned short* vp2 = vbase + (size_t)(kg * 4) * QKVS + dg * 4;
        vr0 = *(const ushort4v*)(vp2);
        vr1 = *(const ushort4v*)(vp2 + QKVS);
        vr2 = *(const ushort4v*)(vp2 + 2 * QKVS);
        vr3 = *(const ushort4v*)(vp2 + 3 * QKVS);
    }

    const float C2 = 0.18033688011112042f;   // (1/sqrt(64)) * log2(e)

    // per-chunk compute: S^T -> softmax -> P -> O += P·V
    auto process = [&](int kt, const short8* qf, f32x4* acc_o, float& m_run, float& l_run,
                       int qw, int myq) {
        f32x4 sacc[4];
#pragma unroll
        for (int mt = 0; mt < 4; ++mt) sacc[mt] = (f32x4){0.f, 0.f, 0.f, 0.f};
#pragma unroll
        for (int mt = 0; mt < 4; ++mt) {
            short8 kf0 = *(const short8*)(&Ks[(mt * 16 + c) * STK + quad * 8]);
            short8 kf1 = *(const short8*)(&Ks[(mt * 16 + c) * STK + 32 + quad * 8]);
            sacc[mt] = __builtin_amdgcn_mfma_f32_16x16x32_bf16(kf0, qf[0], sacc[mt], 0, 0, 0);
            sacc[mt] = __builtin_amdgcn_mfma_f32_16x16x32_bf16(kf1, qf[1], sacc[mt], 0, 0, 0);
        }

        const int kb = kt * 64;
        const bool full = (kb + 63 <= qw) && (kb + 64 <= len);
        float sv[16];
        float mx = -1e30f;
        if (full) {
#pragma unroll
            for (int e = 0; e < 16; ++e) {
                float v = sacc[e >> 2][e & 3];
                sv[e] = v;
                mx = fmaxf(mx, v);
            }
        } else {
#pragma unroll
            for (int mt = 0; mt < 4; ++mt) {
#pragma unroll
                for (int r = 0; r < 4; ++r) {
                    int kpos = kb + mt * 16 + quad * 4 + r;
                    bool valid = (kpos <= myq) && (kpos < len);
                    float v = valid ? sacc[mt][r] : -1e30f;
                    sv[mt * 4 + r] = v;
                    mx = fmaxf(mx, v);
                }
            }
        }
        mx = fmaxf(mx, __shfl_xor(mx, 16));
        mx = fmaxf(mx, __shfl_xor(mx, 32));
        float mnew = fmaxf(m_run, mx * C2);   // log2 domain
        float alpha = fast_exp2(m_run - mnew);
        m_run = mnew;
        l_run *= alpha;

        float ar_[4];
#pragma unroll
        for (int r = 0; r < 4; ++r) ar_[r] = __shfl(alpha, quad * 4 + r);
#pragma unroll
        for (int j = 0; j < 4; ++j)
#pragma unroll
            for (int r = 0; r < 4; ++r) acc_o[j][r] *= ar_[r];

#pragma unroll
        for (int mt = 0; mt < 4; ++mt) {
            float p0 = fast_exp2(__builtin_fmaf(sv[mt * 4 + 0], C2, -mnew));
            float p1 = fast_exp2(__builtin_fmaf(sv[mt * 4 + 1], C2, -mnew));
            float p2 = fast_exp2(__builtin_fmaf(sv[mt * 4 + 2], C2, -mnew));
            float p3 = fast_exp2(__builtin_fmaf(sv[mt * 4 + 3], C2, -mnew));
            l_run += (p0 + p1) + (p2 + p3);
            ushort4v pw;
            pw.x = f2bf_t(p0); pw.y = f2bf_t(p1); pw.z = f2bf_t(p2); pw.w = f2bf_t(p3);
            *(ushort4v*)(&Ps[wave][c * STP + mt * 16 + quad * 4]) = pw;
        }
        // same-wave LDS ordering: DS ops in-order, no barrier needed

#pragma unroll
        for (int ks = 0; ks < 2; ++ks) {
            short8 pf = *(const short8*)(&Ps[wave][c * STP + ks * 32 + quad * 8]);
#pragma unroll
            for (int j = 0; j < 4; ++j) {
                const unsigned short* vb2 = &Vt[(j * 16 + c) * STV + ks * 32 + quad * 8];
                short4v a0 = *(const short4v*)(vb2);
                short4v a1 = *(const short4v*)(vb2 + 4);
                short8 vf = __builtin_shufflevector(a0, a1, 0, 1, 2, 3, 4, 5, 6, 7);
                acc_o[j] = __builtin_amdgcn_mfma_f32_16x16x32_bf16(pf, vf, acc_o[j], 0, 0, 0);
            }
        }
    };

    for (int kt = 0; kt <= ktendB; ++kt) {
        __syncthreads();   // prior iteration's LDS readers done
        // write prefetched tile to LDS
        *(ushort8*)(&Ks[krow * STK + dp * 16]) = kr0;
        *(ushort8*)(&Ks[krow * STK + dp * 16 + 8]) = kr1;
#pragma unroll
        for (int w = 0; w < 4; ++w) {
            ushort4v t;
            t.x = vr0[w]; t.y = vr1[w]; t.z = vr2[w]; t.w = vr3[w];
            *(ushort4v*)(&Vt[(dg * 4 + w) * STV + kg * 4]) = t;
        }
        __syncthreads();

        // issue next tile's global loads (overlap with compute below)
        if (kt < ktendB) {
            const unsigned short* kp2 = kbase + (size_t)((kt + 1) * 64 + krow) * QKVS + dp * 16;
            kr0 = *(const ushort8*)(kp2);
            kr1 = *(const ushort8*)(kp2 + 8);
            const unsigned short* vp2 = vbase + (size_t)((kt + 1) * 64 + kg * 4) * QKVS + dg * 4;
            vr0 = *(const ushort4v*)(vp2);
            vr1 = *(const ushort4v*)(vp2 + QKVS);
            vr2 = *(const ushort4v*)(vp2 + 2 * QKVS);
            vr3 = *(const ushort4v*)(vp2 + 3 * QKVS);
        }

        if (kt <= ktendA)
            process(kt, qfA, accA, mA, lA, qwA, myqA);
        process(kt, qfB, accB, mB, lB, qwB, myqB);
    }

    // ---- finalize both chunks ----
    auto finalize = [&](f32x4* acc_o, float l_run, int qw) {
        l_run += __shfl_xor(l_run, 16);
        l_run += __shfl_xor(l_run, 32);
        float li[4];
#pragma unroll
        for (int r = 0; r < 4; ++r) {
            float lv = __shfl(l_run, quad * 4 + r);
            li[r] = 1.0f / lv;
        }
#pragma unroll
        for (int r = 0; r < 4; ++r) {
            unsigned short* cp = Ctx + ((size_t)(b * Sn + qw + quad * 4 + r)) * Dn + h * 64 + c;
#pragma unroll
            for (int j = 0; j < 4; ++j) {
                cp[j * 16] = f2bf(acc_o[j][r] * li[r]);
            }
        }
    };
    finalize(accA, lA, qwA);
    finalize(accB, lB, qwB);
}

// ---------------- launcher ----------------
extern "C" void kernel_launch(void* const* d_in, const int* in_sizes, int n_in,
                              void* d_out, int out_size, void* d_ws, size_t ws_size,
                              hipStream_t stream) {
    const float* x = (const float*)d_in[0];
    const int* lens = (const int*)d_in[1];
    const float* Wq = (const float*)d_in[2];
    const float* bq = (const float*)d_in[3];
    const float* Wkv = (const float*)d_in[4];
    const float* bkv = (const float*)d_in[5];
    const float* Wo = (const float*)d_in[6];
    const float* bo = (const float*)d_in[7];
    const float* ln_g = (const float*)d_in[8];
    const float* ln_b = (const float*)d_in[9];
    float* out = (float*)d_out;

    char* ws = (char*)d_ws;
    unsigned short* xn_bf = (unsigned short*)ws;                                // 16 MB
    unsigned short* wq_bf = (unsigned short*)(ws + (size_t)16 * 1024 * 1024);   // 2 MB  (Wq | Wkv contiguous -> N=3072 weight)
    unsigned short* wkv_bf = (unsigned short*)(ws + (size_t)18 * 1024 * 1024);  // 4 MB
    unsigned short* wo_bf = (unsigned short*)(ws + (size_t)22 * 1024 * 1024);   // 2 MB
    unsigned short* qkv_bf = (unsigned short*)(ws + (size_t)24 * 1024 * 1024);  // 48 MB (M x 3072)
    unsigned short* ctx_bf = (unsigned short*)(ws + (size_t)72 * 1024 * 1024);  // 16 MB

    // prep: LN (8192 blocks) + weight casts (4096 blocks)
    prep_kernel<<<Mn + 4096, 256, 0, stream>>>(x, ln_g, ln_b, xn_bf,
                                               Wq, Wkv, Wo, wq_bf, wkv_bf, wo_bf);

    // fused QKV = xn @ [Wq;Wkv]^T + [bq;bkv]  (bf16 out, M x 3072)
    {
        dim3 grid(Mn / 128, 3 * Dn / 128);
        gemm_bt<false, true><<<grid, 256, 0, stream>>>(xn_bf, wq_bf, bq, bkv, Dn, nullptr,
                                                       (void*)qkv_bf, Mn, 3 * Dn, Dn);
    }
    // attention -> ctx bf16 (1D grid, batch/head fastest for tail spreading)
    {
        attn_kernel<<<(Sn / 128) * Hn * Bn, 256, 0, stream>>>(qkv_bf, lens, ctx_bf);
    }
    // out = ctx @ Wo^T + bo + x   (fp32 out)
    {
        dim3 grid(Mn / 128, Dn / 128);
        gemm_bt<true, false><<<grid, 256, 0, stream>>>(ctx_bf, wo_bf, bo, bo, Dn, x,
                                                       (void*)out, Mn, Dn, Dn);
    }
}

// Round 7
// 255.648 us; speedup vs baseline: 1.0852x; 1.0852x over previous
//
#include <hip/hip_runtime.h>
#include <hip/hip_bf16.h>

// Problem: B=4, S=2048, D=1024, H=16, DH=64. M = B*S = 8192.
// Pipeline: prep(LN + weight cast) -> fused QKV proj (bf16 mfma, N=3072, BK=64)
//           -> flash attn (bf16 MFMA, paired q-tiles, 3D grid for KV L2 locality)
//           -> out proj (BK=64) + bias + skip (fp32 out)

#define Bn 4
#define Sn 2048
#define Dn 1024
#define Hn 16
#define DHn 64
#define Mn (Bn*Sn)

typedef short short8 __attribute__((ext_vector_type(8)));
typedef short short4v __attribute__((ext_vector_type(4)));
typedef unsigned short ushort8 __attribute__((ext_vector_type(8)));
typedef unsigned short ushort4v __attribute__((ext_vector_type(4)));
typedef float f32x4 __attribute__((ext_vector_type(4)));

__device__ inline float bf2f(unsigned short u) {
    union { unsigned int i; float f; } c;
    c.i = ((unsigned int)u) << 16;
    return c.f;
}

__device__ inline unsigned short f2bf(float f) {
    union { float f; unsigned int i; } c;
    c.f = f;
    unsigned int i = c.i;
    unsigned int lsb = (i >> 16) & 1;
    i += 0x7fffu + lsb;   // round-to-nearest-even
    return (unsigned short)(i >> 16);
}

// truncating fp32->bf16 (fine for p in [0,1])
__device__ inline unsigned short f2bf_t(float f) {
    union { float f; unsigned int i; } c;
    c.f = f;
    return (unsigned short)(c.i >> 16);
}

__device__ __forceinline__ float fast_exp2(float x) {
#if __has_builtin(__builtin_amdgcn_exp2f)
    return __builtin_amdgcn_exp2f(x);
#else
    return exp2f(x);
#endif
}

#if __has_builtin(__builtin_amdgcn_global_load_lds)
#define HAVE_GLDS 1
__device__ __forceinline__ void glds16(const void* g, void* l) {
    __builtin_amdgcn_global_load_lds(
        (const __attribute__((address_space(1))) unsigned int*)g,
        (__attribute__((address_space(3))) unsigned int*)l, 16, 0, 0);
}
#else
#define HAVE_GLDS 0
#endif

// ---------------- prep: LN (blocks 0..8191) + weight casts (blocks 8192..12287) ----------------
__global__ __launch_bounds__(256) void prep_kernel(const float* __restrict__ x,
                                                   const float* __restrict__ g,
                                                   const float* __restrict__ bta,
                                                   unsigned short* __restrict__ xn,
                                                   const float* __restrict__ Wq,
                                                   const float* __restrict__ Wkv,
                                                   const float* __restrict__ Wo,
                                                   unsigned short* __restrict__ oq,
                                                   unsigned short* __restrict__ okv,
                                                   unsigned short* __restrict__ oo) {
    const int t = threadIdx.x;
    if (blockIdx.x >= Mn) {
        int i = (blockIdx.x - Mn) * 256 + t;
        const float* src;
        unsigned short* dst;
        int off;
        if (i < 262144) { src = Wq; dst = oq; off = i; }
        else if (i < 786432) { src = Wkv; dst = okv; off = i - 262144; }
        else { src = Wo; dst = oo; off = i - 786432; }
        float4 v = *(const float4*)(src + (size_t)off * 4);
        ushort4v r;
        r.x = f2bf(v.x); r.y = f2bf(v.y); r.z = f2bf(v.z); r.w = f2bf(v.w);
        *(ushort4v*)(dst + (size_t)off * 4) = r;
        return;
    }
    const int row = blockIdx.x;
    const float* xr = x + (size_t)row * Dn;
    float4 v = *(const float4*)(xr + t * 4);
    float s = v.x + v.y + v.z + v.w;
    float sq = v.x * v.x + v.y * v.y + v.z * v.z + v.w * v.w;
    for (int off = 32; off; off >>= 1) {
        s += __shfl_down(s, off);
        sq += __shfl_down(sq, off);
    }
    __shared__ float ss[4], ssq[4];
    int wave = t >> 6, lane = t & 63;
    if (lane == 0) { ss[wave] = s; ssq[wave] = sq; }
    __syncthreads();
    float tot = ss[0] + ss[1] + ss[2] + ss[3];
    float totq = ssq[0] + ssq[1] + ssq[2] + ssq[3];
    float mean = tot * (1.0f / Dn);
    float var = totq * (1.0f / Dn) - mean * mean;
    float rstd = rsqrtf(var + 1e-5f);
    float4 gv = *(const float4*)(g + t * 4);
    float4 bv = *(const float4*)(bta + t * 4);
    ushort4v r;
    r.x = f2bf((v.x - mean) * rstd * gv.x + bv.x);
    r.y = f2bf((v.y - mean) * rstd * gv.y + bv.y);
    r.z = f2bf((v.z - mean) * rstd * gv.z + bv.z);
    r.w = f2bf((v.w - mean) * rstd * gv.w + bv.w);
    *(ushort4v*)(xn + (size_t)row * Dn + t * 4) = r;
}

// ---------------- bf16 BT-GEMM: C = A(MxK) * Bw(NxK)^T + bias ----------------
// 128x128 tile, 4 waves (2x2), 16x16x32 MFMA. BK=64 staged as TWO 32-col
// panels (each panel = the proven BK=32 layout, glds16-compatible) -> half the
// barrier count of BK=32. LDS 32 KB.
template <bool ADD_SKIP, bool OUT_BF16>
__global__ __launch_bounds__(256, 2) void gemm_bt(const unsigned short* __restrict__ A,
                                                  const unsigned short* __restrict__ Bw,
                                                  const float* __restrict__ bias,
                                                  const float* __restrict__ bias2,
                                                  int bsplit,
                                                  const float* __restrict__ skip,
                                                  void* __restrict__ Cout,
                                                  int M, int N, int K) {
    __shared__ unsigned short As[2 * 128 * 32];   // [panel][row][32]
    __shared__ unsigned short Bs[2 * 128 * 32];
    const int tid = threadIdx.x;
    const int wave = tid >> 6, lane = tid & 63;
    const int warp_m = wave & 1, warp_n = wave >> 1;
    const int bm = blockIdx.x, bn = blockIdx.y;
    const int l4 = lane & 3, lr = lane >> 2;
    const int quad = lane >> 4, r16 = lane & 15;

    f32x4 acc[4][4];
#pragma unroll
    for (int i = 0; i < 4; i++)
#pragma unroll
        for (int j = 0; j < 4; j++) acc[i][j] = (f32x4){0.f, 0.f, 0.f, 0.f};

    for (int k0 = 0; k0 < K; k0 += 64) {
        __syncthreads();   // prev iteration's fragment readers done
#if HAVE_GLDS
#pragma unroll
        for (int ks = 0; ks < 2; ++ks) {
#pragma unroll
            for (int i = 0; i < 2; ++i) {
                int inst = wave + 4 * i;
                glds16(A + (size_t)(bm * 128 + inst * 16 + lr) * K + k0 + ks * 32 + l4 * 8,
                       &As[ks * 4096 + inst * 512]);
                glds16(Bw + (size_t)(bn * 128 + inst * 16 + lr) * K + k0 + ks * 32 + l4 * 8,
                       &Bs[ks * 4096 + inst * 512]);
            }
        }
#else
#pragma unroll
        for (int ks = 0; ks < 2; ++ks) {
#pragma unroll
            for (int i = 0; i < 2; ++i) {
                int inst = wave + 4 * i;
                int row = inst * 16 + lr;
                ushort8 a = *(const ushort8*)(A + (size_t)(bm * 128 + row) * K + k0 + ks * 32 + l4 * 8);
                ushort8 b2 = *(const ushort8*)(Bw + (size_t)(bn * 128 + row) * K + k0 + ks * 32 + l4 * 8);
                *(ushort8*)(As + ks * 4096 + inst * 512 + lane * 8) = a;
                *(ushort8*)(Bs + ks * 4096 + inst * 512 + lane * 8) = b2;
            }
        }
#endif
        __syncthreads();   // vmcnt drain: LDS populated

#pragma unroll
        for (int ks = 0; ks < 2; ++ks) {
            short8 afr[4], bfr[4];
#pragma unroll
            for (int i = 0; i < 4; ++i) {
                int row = warp_m * 64 + i * 16 + r16;
                afr[i] = *(const short8*)(As + ks * 4096 + row * 32 + quad * 8);
            }
#pragma unroll
            for (int j = 0; j < 4; ++j) {
                int row = warp_n * 64 + j * 16 + r16;
                bfr[j] = *(const short8*)(Bs + ks * 4096 + row * 32 + quad * 8);
            }
#pragma unroll
            for (int i = 0; i < 4; ++i)
#pragma unroll
                for (int j = 0; j < 4; ++j)
                    acc[i][j] = __builtin_amdgcn_mfma_f32_16x16x32_bf16(afr[i], bfr[j], acc[i][j], 0, 0, 0);
        }
    }

    const float* bp = (bn * 128 >= bsplit) ? (bias2 - bsplit) : bias;
#pragma unroll
    for (int j = 0; j < 4; ++j) {
        int gcol = bn * 128 + warp_n * 64 + j * 16 + r16;
        float bv = bp[gcol];
#pragma unroll
        for (int i = 0; i < 4; ++i) {
#pragma unroll
            for (int r = 0; r < 4; ++r) {
                int grow = bm * 128 + warp_m * 64 + i * 16 + quad * 4 + r;
                float v = acc[i][j][r] + bv;
                size_t idx = (size_t)grow * N + gcol;
                if (ADD_SKIP) v += skip[idx];
                if (OUT_BF16)
                    ((unsigned short*)Cout)[idx] = f2bf(v);
                else
                    ((float*)Cout)[idx] = v;
            }
        }
    }
}

// ---------------- MFMA flash attention, paired q-tiles ----------------
// grid (S/128, H, B) — qt fastest so the 16 blocks sharing one (b,h)'s KV
// stream are dispatch-adjacent (L2 locality; round-6's batch-fastest 1D grid
// regressed 20 µs by scattering them). Block handles q-tiles qtA and 31-qtA
// sharing K/V staging.
#define STK 72
#define STV 68
#define STP 72
#define QKVS (3 * Dn)   // fused QKV row stride

__global__ __launch_bounds__(256, 4) void attn_kernel(const unsigned short* __restrict__ QKV,
                                                      const int* __restrict__ lens,
                                                      unsigned short* __restrict__ Ctx) {
    const int h = blockIdx.y, b = blockIdx.z;
    const int qtA = blockIdx.x;                 // 0..15
    const int qtB = (Sn / 64 - 1) - qtA;        // 31..16
    const int tid = threadIdx.x;
    const int wave = tid >> 6, lane = tid & 63;
    const int quad = lane >> 4, c = lane & 15;
    const int len = lens[b];
    const int lt = (len - 1) >> 6;
    const int ktendA = min(qtA, lt);
    const int ktendB = min(qtB, lt);            // >= ktendA always
    const int qwA = qtA * 64 + wave * 16;
    const int qwB = qtB * 64 + wave * 16;
    const int myqA = qwA + c, myqB = qwB + c;

    __shared__ unsigned short Ks[64 * STK];
    __shared__ unsigned short Vt[64 * STV];
    __shared__ unsigned short Ps[4][16 * STP];

    // Q fragments for both chunks (B-operand layout)
    short8 qfA[2], qfB[2];
    {
        const unsigned short* qa = QKV + (size_t)(b * Sn + qwA + c) * QKVS + h * 64 + quad * 8;
        qfA[0] = *(const short8*)(qa);
        qfA[1] = *(const short8*)(qa + 32);
        const unsigned short* qb = QKV + (size_t)(b * Sn + qwB + c) * QKVS + h * 64 + quad * 8;
        qfB[0] = *(const short8*)(qb);
        qfB[1] = *(const short8*)(qb + 32);
    }

    f32x4 accA[4], accB[4];
#pragma unroll
    for (int j = 0; j < 4; j++) {
        accA[j] = (f32x4){0.f, 0.f, 0.f, 0.f};
        accB[j] = (f32x4){0.f, 0.f, 0.f, 0.f};
    }
    float mA = -1e30f, lA = 0.f, mB = -1e30f, lB = 0.f;

    // staging thread mappings
    const int krow = tid >> 2, dp = tid & 3;   // K: row krow, 16-col chunk dp
    const int kg = tid >> 4, dg = tid & 15;    // V: k rows kg*4..+3, dh cols dg*4..+3
    const unsigned short* kbase = QKV + (size_t)(b * Sn) * QKVS + Dn + h * 64;        // K cols
    const unsigned short* vbase = QKV + (size_t)(b * Sn) * QKVS + 2 * Dn + h * 64;    // V cols

    // prologue: prefetch tile 0
    ushort8 kr0, kr1;
    ushort4v vr0, vr1, vr2, vr3;
    {
        const unsigned short* kp2 = kbase + (size_t)krow * QKVS + dp * 16;
        kr0 = *(const ushort8*)(kp2);
        kr1 = *(const ushort8*)(kp2 + 8);
        const unsigned short* vp2 = vbase + (size_t)(kg * 4) * QKVS + dg * 4;
        vr0 = *(const ushort4v*)(vp2);
        vr1 = *(const ushort4v*)(vp2 + QKVS);
        vr2 = *(const ushort4v*)(vp2 + 2 * QKVS);
        vr3 = *(const ushort4v*)(vp2 + 3 * QKVS);
    }

    const float C2 = 0.18033688011112042f;   // (1/sqrt(64)) * log2(e)

    // per-chunk compute: S^T -> softmax -> P -> O += P·V
    auto process = [&](int kt, const short8* qf, f32x4* acc_o, float& m_run, float& l_run,
                       int qw, int myq) {
        f32x4 sacc[4];
#pragma unroll
        for (int mt = 0; mt < 4; ++mt) sacc[mt] = (f32x4){0.f, 0.f, 0.f, 0.f};
#pragma unroll
        for (int mt = 0; mt < 4; ++mt) {
            short8 kf0 = *(const short8*)(&Ks[(mt * 16 + c) * STK + quad * 8]);
            short8 kf1 = *(const short8*)(&Ks[(mt * 16 + c) * STK + 32 + quad * 8]);
            sacc[mt] = __builtin_amdgcn_mfma_f32_16x16x32_bf16(kf0, qf[0], sacc[mt], 0, 0, 0);
            sacc[mt] = __builtin_amdgcn_mfma_f32_16x16x32_bf16(kf1, qf[1], sacc[mt], 0, 0, 0);
        }

        const int kb = kt * 64;
        const bool full = (kb + 63 <= qw) && (kb + 64 <= len);
        float sv[16];
        float mx = -1e30f;
        if (full) {
#pragma unroll
            for (int e = 0; e < 16; ++e) {
                float v = sacc[e >> 2][e & 3];
                sv[e] = v;
                mx = fmaxf(mx, v);
            }
        } else {
#pragma unroll
            for (int mt = 0; mt < 4; ++mt) {
#pragma unroll
                for (int r = 0; r < 4; ++r) {
                    int kpos = kb + mt * 16 + quad * 4 + r;
                    bool valid = (kpos <= myq) && (kpos < len);
                    float v = valid ? sacc[mt][r] : -1e30f;
                    sv[mt * 4 + r] = v;
                    mx = fmaxf(mx, v);
                }
            }
        }
        mx = fmaxf(mx, __shfl_xor(mx, 16));
        mx = fmaxf(mx, __shfl_xor(mx, 32));
        float mnew = fmaxf(m_run, mx * C2);   // log2 domain
        float alpha = fast_exp2(m_run - mnew);
        m_run = mnew;
        l_run *= alpha;

        float ar_[4];
#pragma unroll
        for (int r = 0; r < 4; ++r) ar_[r] = __shfl(alpha, quad * 4 + r);
#pragma unroll
        for (int j = 0; j < 4; ++j)
#pragma unroll
            for (int r = 0; r < 4; ++r) acc_o[j][r] *= ar_[r];

#pragma unroll
        for (int mt = 0; mt < 4; ++mt) {
            float p0 = fast_exp2(__builtin_fmaf(sv[mt * 4 + 0], C2, -mnew));
            float p1 = fast_exp2(__builtin_fmaf(sv[mt * 4 + 1], C2, -mnew));
            float p2 = fast_exp2(__builtin_fmaf(sv[mt * 4 + 2], C2, -mnew));
            float p3 = fast_exp2(__builtin_fmaf(sv[mt * 4 + 3], C2, -mnew));
            l_run += (p0 + p1) + (p2 + p3);
            ushort4v pw;
            pw.x = f2bf_t(p0); pw.y = f2bf_t(p1); pw.z = f2bf_t(p2); pw.w = f2bf_t(p3);
            *(ushort4v*)(&Ps[wave][c * STP + mt * 16 + quad * 4]) = pw;
        }
        // same-wave LDS ordering: DS ops in-order, no barrier needed

#pragma unroll
        for (int ks = 0; ks < 2; ++ks) {
            short8 pf = *(const short8*)(&Ps[wave][c * STP + ks * 32 + quad * 8]);
#pragma unroll
            for (int j = 0; j < 4; ++j) {
                const unsigned short* vb2 = &Vt[(j * 16 + c) * STV + ks * 32 + quad * 8];
                short4v a0 = *(const short4v*)(vb2);
                short4v a1 = *(const short4v*)(vb2 + 4);
                short8 vf = __builtin_shufflevector(a0, a1, 0, 1, 2, 3, 4, 5, 6, 7);
                acc_o[j] = __builtin_amdgcn_mfma_f32_16x16x32_bf16(pf, vf, acc_o[j], 0, 0, 0);
            }
        }
    };

    for (int kt = 0; kt <= ktendB; ++kt) {
        __syncthreads();   // prior iteration's LDS readers done
        // write prefetched tile to LDS
        *(ushort8*)(&Ks[krow * STK + dp * 16]) = kr0;
        *(ushort8*)(&Ks[krow * STK + dp * 16 + 8]) = kr1;
#pragma unroll
        for (int w = 0; w < 4; ++w) {
            ushort4v t;
            t.x = vr0[w]; t.y = vr1[w]; t.z = vr2[w]; t.w = vr3[w];
            *(ushort4v*)(&Vt[(dg * 4 + w) * STV + kg * 4]) = t;
        }
        __syncthreads();

        // issue next tile's global loads (overlap with compute below)
        if (kt < ktendB) {
            const unsigned short* kp2 = kbase + (size_t)((kt + 1) * 64 + krow) * QKVS + dp * 16;
            kr0 = *(const ushort8*)(kp2);
            kr1 = *(const ushort8*)(kp2 + 8);
            const unsigned short* vp2 = vbase + (size_t)((kt + 1) * 64 + kg * 4) * QKVS + dg * 4;
            vr0 = *(const ushort4v*)(vp2);
            vr1 = *(const ushort4v*)(vp2 + QKVS);
            vr2 = *(const ushort4v*)(vp2 + 2 * QKVS);
            vr3 = *(const ushort4v*)(vp2 + 3 * QKVS);
        }

        if (kt <= ktendA)
            process(kt, qfA, accA, mA, lA, qwA, myqA);
        process(kt, qfB, accB, mB, lB, qwB, myqB);
    }

    // ---- finalize both chunks ----
    auto finalize = [&](f32x4* acc_o, float l_run, int qw) {
        l_run += __shfl_xor(l_run, 16);
        l_run += __shfl_xor(l_run, 32);
        float li[4];
#pragma unroll
        for (int r = 0; r < 4; ++r) {
            float lv = __shfl(l_run, quad * 4 + r);
            li[r] = 1.0f / lv;
        }
#pragma unroll
        for (int r = 0; r < 4; ++r) {
            unsigned short* cp = Ctx + ((size_t)(b * Sn + qw + quad * 4 + r)) * Dn + h * 64 + c;
#pragma unroll
            for (int j = 0; j < 4; ++j) {
                cp[j * 16] = f2bf(acc_o[j][r] * li[r]);
            }
        }
    };
    finalize(accA, lA, qwA);
    finalize(accB, lB, qwB);
}

// ---------------- launcher ----------------
extern "C" void kernel_launch(void* const* d_in, const int* in_sizes, int n_in,
                              void* d_out, int out_size, void* d_ws, size_t ws_size,
                              hipStream_t stream) {
    const float* x = (const float*)d_in[0];
    const int* lens = (const int*)d_in[1];
    const float* Wq = (const float*)d_in[2];
    const float* bq = (const float*)d_in[3];
    const float* Wkv = (const float*)d_in[4];
    const float* bkv = (const float*)d_in[5];
    const float* Wo = (const float*)d_in[6];
    const float* bo = (const float*)d_in[7];
    const float* ln_g = (const float*)d_in[8];
    const float* ln_b = (const float*)d_in[9];
    float* out = (float*)d_out;

    char* ws = (char*)d_ws;
    unsigned short* xn_bf = (unsigned short*)ws;                                // 16 MB
    unsigned short* wq_bf = (unsigned short*)(ws + (size_t)16 * 1024 * 1024);   // 2 MB  (Wq | Wkv contiguous -> N=3072 weight)
    unsigned short* wkv_bf = (unsigned short*)(ws + (size_t)18 * 1024 * 1024);  // 4 MB
    unsigned short* wo_bf = (unsigned short*)(ws + (size_t)22 * 1024 * 1024);   // 2 MB
    unsigned short* qkv_bf = (unsigned short*)(ws + (size_t)24 * 1024 * 1024);  // 48 MB (M x 3072)
    unsigned short* ctx_bf = (unsigned short*)(ws + (size_t)72 * 1024 * 1024);  // 16 MB

    // prep: LN (8192 blocks) + weight casts (4096 blocks)
    prep_kernel<<<Mn + 4096, 256, 0, stream>>>(x, ln_g, ln_b, xn_bf,
                                               Wq, Wkv, Wo, wq_bf, wkv_bf, wo_bf);

    // fused QKV = xn @ [Wq;Wkv]^T + [bq;bkv]  (bf16 out, M x 3072)
    {
        dim3 grid(Mn / 128, 3 * Dn / 128);
        gemm_bt<false, true><<<grid, 256, 0, stream>>>(xn_bf, wq_bf, bq, bkv, Dn, nullptr,
                                                       (void*)qkv_bf, Mn, 3 * Dn, Dn);
    }
    // attention -> ctx bf16 (3D grid: qt fastest for KV L2 locality)
    {
        dim3 grid(Sn / 128, Hn, Bn);
        attn_kernel<<<grid, 256, 0, stream>>>(qkv_bf, lens, ctx_bf);
    }
    // out = ctx @ Wo^T + bo + x   (fp32 out)
    {
        dim3 grid(Mn / 128, Dn / 128);
        gemm_bt<true, false><<<grid, 256, 0, stream>>>(ctx_bf, wo_bf, bo, bo, Dn, x,
                                                       (void*)out, Mn, Dn, Dn);
    }
}